// Round 1
// baseline (5698.437 us; speedup 1.0000x reference)
//
#include <hip/hip_runtime.h>
#include <math.h>

#define BATCH 256
#define HID   512
#define DIN   256
#define SEQ   512
#define HIST  2048
#define NBLK  256     // 8 batch-groups x 32 u-tiles
#define NGRP  8
#define GB    32      // batches per group

typedef __attribute__((ext_vector_type(8))) short short8;
typedef __attribute__((ext_vector_type(4))) float floatx4;
typedef __attribute__((ext_vector_type(8))) float floatx8;
typedef unsigned long long ull;
typedef unsigned int uint;

__device__ __forceinline__ unsigned short f32_bf16_rtne(float f) {
    uint u = __builtin_bit_cast(uint, f);
    uint r = u + 0x7FFFu + ((u >> 16) & 1u);
    return (unsigned short)(r >> 16);
}
__device__ __forceinline__ float bf16_f32(unsigned short s) {
    uint u = ((uint)s) << 16;
    return __builtin_bit_cast(float, u);
}
__device__ __forceinline__ float sigmoidf_(float v) {
    return 1.0f / (1.0f + __expf(-v));
}

// fragment-layout word index for packed h within one group's buffer:
// reader wave lane l=(quad,n16) for (K,mt) reads word ((K*2+mt)*64+l)*8 + j
__device__ __forceinline__ int h_widx(int b_local, int u) {
    return ((u >> 5) * 2 + (b_local >> 4)) * 512 +
           ((u >> 3) & 3) * 128 + (b_local & 15) * 8 + (u & 7);
}

// split fp32 -> (hi, lo) bf16 pair (weights)
__global__ __launch_bounds__(256) void split_kernel(
    const float* __restrict__ src, short* __restrict__ hi, short* __restrict__ lo, int n)
{
    int i = blockIdx.x * 256 + threadIdx.x;
    if (i < n) {
        float v = src[i];
        unsigned short h = f32_bf16_rtne(v);
        hi[i] = (short)h;
        lo[i] = (short)f32_bf16_rtne(v - bf16_f32(h));
    }
}

// initial hidden -> packed frag-layout buffer 0 (value in low 32b, tag=0 in high 32b)
__global__ __launch_bounds__(256) void pack_h_init(
    const float* __restrict__ hidden, ull* __restrict__ hp0)
{
    int i = blockIdx.x * 256 + threadIdx.x;   // 131072
    int b = i >> 9, u = i & 511;
    int g = b >> 5, bl = b & 31;
    float v = hidden[i];
    unsigned short hi = f32_bf16_rtne(v);
    unsigned short lo = f32_bf16_rtne(v - bf16_f32(hi));
    hp0[(size_t)g * 16384 + h_widx(bl, u)] = (ull)((uint)hi | ((uint)lo << 16));
}

// Persistent GRU. 256 blocks x 512 thr (8 waves). Block (g = bid&7,
// ublk = bid>>3): 32 batches x 16 hidden units. UNIFORM wave roles: wave w
// owns x ktile w (K=32) and h ktiles 2w,2w+1 (K=64); weights register-
// resident (72 VGPR). h exchanged as self-validating 64-bit atoms
// (value32 | step-tag32) via relaxed agent-scope atomics: no flags, no
// producer drain, optimistic early loads + tag-check retry.
__global__ __launch_bounds__(512, 2) void gru_persistent(
    const float* __restrict__ x,        // [SEQ][BATCH][DIN]
    const float* __restrict__ hidden,   // [1][BATCH][HID]
    ull* __restrict__ hpA, ull* __restrict__ hpB,   // packed h ping-pong (value|tag)
    const short* __restrict__ wih_hi, const short* __restrict__ wih_lo,
    const short* __restrict__ whh_hi, const short* __restrict__ whh_lo)
{
    const int bid  = blockIdx.x;
    const int g    = bid & 7;
    const int ublk = bid >> 3;
    const int u0   = ublk * 16;
    const int tid  = threadIdx.x;
    const int w    = tid >> 6;
    const int lane = tid & 63;
    const int quad = lane >> 4;
    const int n16  = lane & 15;
    const int mbase = g * GB;

    // ---- register-resident weight fragments: slot0 = x ktile w, slots 1,2 = h ktiles 2w,2w+1
    short8 Bh[3][3], Bl[3][3];
    #pragma unroll
    for (int gt = 0; gt < 3; ++gt) {
        const int row = gt * HID + u0 + n16;
        Bh[gt][0] = *(const short8*)(wih_hi + (size_t)row * DIN + w * 32 + quad * 8);
        Bl[gt][0] = *(const short8*)(wih_lo + (size_t)row * DIN + w * 32 + quad * 8);
        #pragma unroll
        for (int s = 0; s < 2; ++s) {
            const int K0h = w * 64 + s * 32;
            Bh[gt][1 + s] = *(const short8*)(whh_hi + (size_t)row * HID + K0h + quad * 8);
            Bl[gt][1 + s] = *(const short8*)(whh_lo + (size_t)row * HID + K0h + quad * 8);
        }
    }

    // ---- this thread's output element: h_prev stays in a register ----
    const int ob = tid >> 4;          // b_local 0..31
    const int ou = tid & 15;          // u_local 0..15
    float hp = hidden[(size_t)(mbase + ob) * HID + (u0 + ou)];
    const int my_widx = h_widx(ob, u0 + ou);

    __shared__ float P8[8][2][4][16][20];  // [wave][mt][acc][u_col][b_row+pad] = 80 KiB

#define MFMA3(AH, AL, BH, BL, ACC)                                        \
    ACC = __builtin_amdgcn_mfma_f32_16x16x32_bf16(AH, BH, ACC, 0, 0, 0);  \
    ACC = __builtin_amdgcn_mfma_f32_16x16x32_bf16(AL, BH, ACC, 0, 0, 0);  \
    ACC = __builtin_amdgcn_mfma_f32_16x16x32_bf16(AH, BL, ACC, 0, 0, 0);

    for (int t = 0; t < SEQ; ++t) {
        const ull* hb = ((t & 1) ? hpB : hpA) + (size_t)g * 16384;
        ull*       hd = ((t & 1) ? hpA : hpB) + (size_t)g * 16384;

        // ---- x loads first (vmcnt retires in issue order: keep x oldest) ----
        const float* xt = x + (size_t)t * BATCH * DIN;
        const floatx8 xv0 = *(const floatx8*)(xt + (size_t)(mbase + n16) * DIN + w * 32 + quad * 8);
        const floatx8 xv1 = *(const floatx8*)(xt + (size_t)(mbase + 16 + n16) * DIN + w * 32 + quad * 8);

        // ---- optimistic h loads: issued before producers are known-done;
        //      tag-check below retries stale words ----
        ull hv[2][2][8];
        #pragma unroll
        for (int s = 0; s < 2; ++s)
            #pragma unroll
            for (int mt = 0; mt < 2; ++mt) {
                const ull* base = hb + (size_t)(((2 * w + s) * 2 + mt) * 64 + lane) * 8;
                #pragma unroll
                for (int j = 0; j < 8; ++j)
                    hv[s][mt][j] = __hip_atomic_load(base + j, __ATOMIC_RELAXED,
                                                     __HIP_MEMORY_SCOPE_AGENT);
            }

        floatx4 acc[2][4];
        #pragma unroll
        for (int mt = 0; mt < 2; ++mt)
            #pragma unroll
            for (int a = 0; a < 4; ++a)
                acc[mt][a] = (floatx4){0.f, 0.f, 0.f, 0.f};

        // ---- x part ----
        #pragma unroll
        for (int mt = 0; mt < 2; ++mt) {
            const floatx8 xv = mt ? xv1 : xv0;
            short8 Ah, Al;
            #pragma unroll
            for (int j = 0; j < 8; ++j) {
                const float v = xv[j];
                const unsigned short hbw = f32_bf16_rtne(v);
                Ah[j] = (short)hbw;
                Al[j] = (short)f32_bf16_rtne(v - bf16_f32(hbw));
            }
            MFMA3(Ah, Al, Bh[0][0], Bl[0][0], acc[mt][0])
            MFMA3(Ah, Al, Bh[1][0], Bl[1][0], acc[mt][1])
            MFMA3(Ah, Al, Bh[2][0], Bl[2][0], acc[mt][2])
        }

        // ---- tag check + retry: value|tag in one 8B atom, no tearing ----
        {
            const uint want = (uint)t;
            bool ok;
            do {
                ok = true;
                #pragma unroll
                for (int s = 0; s < 2; ++s)
                    #pragma unroll
                    for (int mt = 0; mt < 2; ++mt) {
                        const ull* base = hb + (size_t)(((2 * w + s) * 2 + mt) * 64 + lane) * 8;
                        #pragma unroll
                        for (int j = 0; j < 8; ++j)
                            if ((uint)(hv[s][mt][j] >> 32) != want) {
                                hv[s][mt][j] = __hip_atomic_load(base + j, __ATOMIC_RELAXED,
                                                                 __HIP_MEMORY_SCOPE_AGENT);
                                ok = false;
                            }
                    }
            } while (!__all(ok));
        }

        // ---- h part ----
        #pragma unroll
        for (int s = 0; s < 2; ++s)
            #pragma unroll
            for (int mt = 0; mt < 2; ++mt) {
                union { unsigned short u16[16]; short8 s8[2]; } U;
                #pragma unroll
                for (int j = 0; j < 8; ++j) {
                    const uint wv = (uint)hv[s][mt][j];
                    U.u16[j]     = (unsigned short)(wv & 0xFFFFu);   // hi parts
                    U.u16[8 + j] = (unsigned short)(wv >> 16);       // lo parts
                }
                const short8 Ah = U.s8[0];
                const short8 Al = U.s8[1];
                MFMA3(Ah, Al, Bh[0][1 + s], Bl[0][1 + s], acc[mt][0])
                MFMA3(Ah, Al, Bh[1][1 + s], Bl[1][1 + s], acc[mt][1])
                MFMA3(Ah, Al, Bh[2][1 + s], Bl[2][1 + s], acc[mt][3])
            }
#undef MFMA3

        // ---- single-shot K-split reduction: 8 regions, ONE barrier ----
        #pragma unroll
        for (int mt = 0; mt < 2; ++mt)
            #pragma unroll
            for (int a = 0; a < 4; ++a)
                *(floatx4*)&P8[w][mt][a][n16][quad * 4] = acc[mt][a];
        __syncthreads();

        float sR = 0.f, sZ = 0.f, sNI = 0.f, sNH = 0.f;
        {
            const int mt = ob >> 4, rw = ob & 15;
            #pragma unroll
            for (int r = 0; r < 8; ++r) {
                sR  += P8[r][mt][0][ou][rw];
                sZ  += P8[r][mt][1][ou][rw];
                sNI += P8[r][mt][2][ou][rw];
                sNH += P8[r][mt][3][ou][rw];
            }
        }
        __syncthreads();   // protect P8 reuse; no LLC drain on the critical path

        // ---- epilogue: gates, h update, tagged store (tag = t+1) ----
        {
            const float r = sigmoidf_(sR);
            const float z = sigmoidf_(sZ);
            const float n = tanhf(sNI + r * sNH);
            const float hn = (1.0f - z) * n + z * hp;
            hp = hn;
            const unsigned short hbi = f32_bf16_rtne(hn);
            const unsigned short lbi = f32_bf16_rtne(hn - bf16_f32(hbi));
            const ull word = (ull)((uint)hbi | ((uint)lbi << 16)) |
                             ((ull)(uint)(t + 1) << 32);
            __hip_atomic_store(hd + my_widx, word, __ATOMIC_RELAXED,
                               __HIP_MEMORY_SCOPE_AGENT);
        }
    }
}

// --- attention / sigma / mu (reads packed final h, low 32b of each atom) ---
__global__ __launch_bounds__(256) void attn_kernel(
    const ull* __restrict__ hpk,         // packed frag-layout final h
    const float* __restrict__ external,
    const float* __restrict__ w_alpha,
    const float* __restrict__ w_sigma,
    float* __restrict__ mu,
    float* __restrict__ inv_sig,
    float* __restrict__ log_det)
{
    const int b = blockIdx.x;
    const int t = threadIdx.x;

    __shared__ float hs[HID];
    __shared__ float al[HIST];
    __shared__ float red[256];

    const int g = b >> 5, bl = b & 31;
    for (int k = t; k < HID; k += 256) {
        const uint wv = (uint)hpk[(size_t)g * 16384 + h_widx(bl, k)];
        hs[k] = bf16_f32((unsigned short)(wv & 0xFFFF)) +
                bf16_f32((unsigned short)(wv >> 16));
    }
    __syncthreads();

    const float4* hs4 = (const float4*)hs;

    float lg[8];
    #pragma unroll
    for (int i = 0; i < 8; ++i) {
        const int e = t + 256 * i;
        const float4* wr = (const float4*)(w_alpha + (size_t)e * HID);
        float acc = 0.f;
        #pragma unroll 4
        for (int k = 0; k < HID / 4; ++k) {
            const float4 w4 = wr[k];
            const float4 h4 = hs4[k];
            acc += w4.x * h4.x + w4.y * h4.y + w4.z * h4.z + w4.w * h4.w;
        }
        lg[i] = acc;
    }

    float m = lg[0];
    #pragma unroll
    for (int i = 1; i < 8; ++i) m = fmaxf(m, lg[i]);
    red[t] = m;
    __syncthreads();
    for (int off = 128; off > 0; off >>= 1) {
        if (t < off) red[t] = fmaxf(red[t], red[t + off]);
        __syncthreads();
    }
    m = red[0];
    __syncthreads();

    float s = 0.f;
    #pragma unroll
    for (int i = 0; i < 8; ++i) {
        const float v = __expf(lg[i] - m);
        al[t + 256 * i] = v;
        s += v;
    }
    red[t] = s;
    __syncthreads();
    for (int off = 128; off > 0; off >>= 1) {
        if (t < off) red[t] += red[t + off];
        __syncthreads();
    }
    s = red[0];
    const float inv_s = 1.0f / s;
    __syncthreads();

    const int d = t;
    float acc_mu = 0.f;
    #pragma unroll 8
    for (int e = 0; e < HIST; ++e) {
        acc_mu += al[e] * external[(size_t)e * DIN + d];
    }
    mu[(size_t)b * DIN + d] = acc_mu * inv_s;

    const float4* ws = (const float4*)(w_sigma + (size_t)d * HID);
    float sl = 0.f;
    #pragma unroll 4
    for (int k = 0; k < HID / 4; ++k) {
        const float4 w4 = ws[k];
        const float4 h4 = hs4[k];
        sl += w4.x * h4.x + w4.y * h4.y + w4.z * h4.z + w4.w * h4.w;
    }
    inv_sig[(size_t)b * DIN + d] = __expf(-sl);

    red[t] = sl;
    __syncthreads();
    for (int off = 128; off > 0; off >>= 1) {
        if (t < off) red[t] += red[t + off];
        __syncthreads();
    }
    if (t == 0) log_det[b] = red[0];
}

__global__ __launch_bounds__(256) void out_kernel(
    const float* __restrict__ x,
    const float* __restrict__ mu,
    const float* __restrict__ inv_sig,
    const float* __restrict__ log_det,
    float* __restrict__ out)
{
    const int s = blockIdx.x;
    const int b = threadIdx.x;
    const float4* xr = (const float4*)(x + ((size_t)s * BATCH + b) * DIN);
    const float4* mr = (const float4*)(mu + (size_t)b * DIN);
    const float4* ir = (const float4*)(inv_sig + (size_t)b * DIN);

    float maha = 0.f;
    #pragma unroll 8
    for (int k = 0; k < DIN / 4; ++k) {
        const float4 xv = xr[k];
        const float4 mv = mr[k];
        const float4 iv = ir[k];
        const float t0 = (xv.x - mv.x) * iv.x;
        const float t1 = (xv.y - mv.y) * iv.y;
        const float t2 = (xv.z - mv.z) * iv.z;
        const float t3 = (xv.w - mv.w) * iv.w;
        maha += t0 * t0 + t1 * t1 + t2 * t2 + t3 * t3;
    }
    const float LOG2PI = 1.8378770664093453f;
    out[(size_t)s * BATCH + b] = -0.5f * (maha + (float)DIN * LOG2PI) - log_det[b];
}

extern "C" void kernel_launch(void* const* d_in, const int* in_sizes, int n_in,
                              void* d_out, int out_size, void* d_ws, size_t ws_size,
                              hipStream_t stream)
{
    const float* x        = (const float*)d_in[0];
    const float* hidden   = (const float*)d_in[1];
    const float* external = (const float*)d_in[2];
    const float* w_ih     = (const float*)d_in[3];
    const float* w_hh     = (const float*)d_in[4];
    const float* w_alpha  = (const float*)d_in[5];
    const float* w_sigma  = (const float*)d_in[6];

    const int NH  = BATCH * HID;      // 131072
    const int NIH = 3 * HID * DIN;    // 393216
    const int NHH = 3 * HID * HID;    // 786432

    char* p = (char*)d_ws;
    ull* hpA = (ull*)p;               p += (size_t)NH * 8;
    ull* hpB = (ull*)p;               p += (size_t)NH * 8;
    short* wih_hi = (short*)p;        p += (size_t)NIH * 2;
    short* wih_lo = (short*)p;        p += (size_t)NIH * 2;
    short* whh_hi = (short*)p;        p += (size_t)NHH * 2;
    short* whh_lo = (short*)p;        p += (size_t)NHH * 2;
    float* mu      = (float*)p;       p += (size_t)BATCH * DIN * 4;
    float* inv_sig = (float*)p;       p += (size_t)BATCH * DIN * 4;
    float* log_det = (float*)p;       p += (size_t)BATCH * 4;

    // hpB tags must start != 1 (consumers at t=1 expect tag 1); hpA is fully
    // written (tag 0) by pack_h_init.
    (void)hipMemsetAsync(hpB, 0, (size_t)NH * 8, stream);

    split_kernel<<<(NIH + 255) / 256, 256, 0, stream>>>(w_ih, wih_hi, wih_lo, NIH);
    split_kernel<<<(NHH + 255) / 256, 256, 0, stream>>>(w_hh, whh_hi, whh_lo, NHH);
    pack_h_init<<<(NH + 255) / 256, 256, 0, stream>>>(hidden, hpA);

    gru_persistent<<<dim3(NBLK), dim3(512), 0, stream>>>(
        x, hidden, hpA, hpB, wih_hi, wih_lo, whh_hi, whh_lo);
    // t=511 (odd) writes hpA -> final packed h in hpA

    attn_kernel<<<dim3(BATCH), dim3(256), 0, stream>>>(
        hpA, external, w_alpha, w_sigma, mu, inv_sig, log_det);

    out_kernel<<<dim3(SEQ), dim3(256), 0, stream>>>(
        x, mu, inv_sig, log_det, (float*)d_out);
}

// Round 2
// 3051.038 us; speedup vs baseline: 1.8677x; 1.8677x over previous
//
#include <hip/hip_runtime.h>
#include <math.h>

#define BATCH 256
#define HID   512
#define DIN   256
#define SEQ   512
#define HIST  2048
#define NBLK  256     // 8 batch-groups x 32 u-tiles
#define NGRP  8
#define GB    32      // batches per group

typedef __attribute__((ext_vector_type(8))) short short8;
typedef __attribute__((ext_vector_type(4))) float floatx4;
typedef __attribute__((ext_vector_type(8))) float floatx8;
typedef unsigned long long ull;
typedef unsigned int uint;

__device__ __forceinline__ unsigned short f32_bf16_rtne(float f) {
    uint u = __builtin_bit_cast(uint, f);
    uint r = u + 0x7FFFu + ((u >> 16) & 1u);
    return (unsigned short)(r >> 16);
}
__device__ __forceinline__ float bf16_f32(unsigned short s) {
    uint u = ((uint)s) << 16;
    return __builtin_bit_cast(float, u);
}
__device__ __forceinline__ float sigmoidf_(float v) {
    return 1.0f / (1.0f + __expf(-v));
}

// fragment-layout word index for packed h within one group's buffer:
// reader wave lane l=(quad,n16) for (K,mt) reads word ((K*2+mt)*64+l)*8 + j
__device__ __forceinline__ int h_widx(int b_local, int u) {
    return ((u >> 5) * 2 + (b_local >> 4)) * 512 +
           ((u >> 3) & 3) * 128 + (b_local & 15) * 8 + (u & 7);
}

// LDS-only barrier: does NOT drain vmcnt (h-store acks stay off the
// critical path; tag validation provides the cross-block ordering).
__device__ __forceinline__ void lds_barrier() {
    __builtin_amdgcn_sched_barrier(0);
    asm volatile("s_waitcnt lgkmcnt(0)" ::: "memory");
    __builtin_amdgcn_s_barrier();
    __builtin_amdgcn_sched_barrier(0);
}

// split fp32 -> (hi, lo) bf16 pair (weights)
__global__ __launch_bounds__(256) void split_kernel(
    const float* __restrict__ src, short* __restrict__ hi, short* __restrict__ lo, int n)
{
    int i = blockIdx.x * 256 + threadIdx.x;
    if (i < n) {
        float v = src[i];
        unsigned short h = f32_bf16_rtne(v);
        hi[i] = (short)h;
        lo[i] = (short)f32_bf16_rtne(v - bf16_f32(h));
    }
}

// initial hidden -> packed frag-layout buffer 0 (tag bits = 0 => gen 0)
__global__ __launch_bounds__(256) void pack_h_init(
    const float* __restrict__ hidden, uint* __restrict__ hp0)
{
    int i = blockIdx.x * 256 + threadIdx.x;   // 131072
    int b = i >> 9, u = i & 511;
    int g = b >> 5, bl = b & 31;
    float v = hidden[i];
    unsigned short hi = f32_bf16_rtne(v);
    unsigned short lo = f32_bf16_rtne(v - bf16_f32(hi));
    lo = (unsigned short)(lo & 0xFFFCu);      // tag = 0
    hp0[(size_t)g * 16384 + h_widx(bl, u)] = (uint)hi | ((uint)lo << 16);
}

// Persistent GRU. 256 blocks x 512 thr (8 waves). Block (g = bid&7,
// ublk = bid>>3): 32 batches x 16 hidden units. Uniform wave roles: wave w
// owns x ktile w (K=32) and h ktiles 2w,2w+1; weights register-resident.
// h exchanged as 4B packed (hi|lo) words with a 2-bit generation tag stolen
// from lo's low mantissa bits (skew between any producer/consumer pair is
// <=2 steps, so mod-4 tags are unambiguous). No flags, no producer drain:
// optimistic early loads + tag-check retry with s_sleep backoff. Barriers
// are lgkmcnt-only (no vmcnt drain on the critical path).
__global__ __launch_bounds__(512, 2) void gru_persistent(
    const float* __restrict__ x,        // [SEQ][BATCH][DIN]
    const float* __restrict__ hidden,   // [1][BATCH][HID]
    uint* __restrict__ hpA, uint* __restrict__ hpB,   // packed h ping-pong
    const short* __restrict__ wih_hi, const short* __restrict__ wih_lo,
    const short* __restrict__ whh_hi, const short* __restrict__ whh_lo)
{
    const int bid  = blockIdx.x;
    const int g    = bid & 7;
    const int ublk = bid >> 3;
    const int u0   = ublk * 16;
    const int tid  = threadIdx.x;
    const int w    = tid >> 6;
    const int lane = tid & 63;
    const int quad = lane >> 4;
    const int n16  = lane & 15;
    const int mbase = g * GB;

    // ---- register-resident weight fragments: slot0 = x ktile w, slots 1,2 = h ktiles 2w,2w+1
    short8 Bh[3][3], Bl[3][3];
    #pragma unroll
    for (int gt = 0; gt < 3; ++gt) {
        const int row = gt * HID + u0 + n16;
        Bh[gt][0] = *(const short8*)(wih_hi + (size_t)row * DIN + w * 32 + quad * 8);
        Bl[gt][0] = *(const short8*)(wih_lo + (size_t)row * DIN + w * 32 + quad * 8);
        #pragma unroll
        for (int s = 0; s < 2; ++s) {
            const int K0h = w * 64 + s * 32;
            Bh[gt][1 + s] = *(const short8*)(whh_hi + (size_t)row * HID + K0h + quad * 8);
            Bl[gt][1 + s] = *(const short8*)(whh_lo + (size_t)row * HID + K0h + quad * 8);
        }
    }

    // ---- this thread's output element: h_prev stays in a register ----
    const int ob = tid >> 4;          // b_local 0..31
    const int ou = tid & 15;          // u_local 0..15
    float hp = hidden[(size_t)(mbase + ob) * HID + (u0 + ou)];
    const int my_widx = h_widx(ob, u0 + ou);

    __shared__ float P8[8][2][4][16][20];  // [wave][mt][acc][u_col][b_row+pad] = 80 KiB

#define MFMA3(AH, AL, BH, BL, ACC)                                        \
    ACC = __builtin_amdgcn_mfma_f32_16x16x32_bf16(AH, BH, ACC, 0, 0, 0);  \
    ACC = __builtin_amdgcn_mfma_f32_16x16x32_bf16(AL, BH, ACC, 0, 0, 0);  \
    ACC = __builtin_amdgcn_mfma_f32_16x16x32_bf16(AH, BL, ACC, 0, 0, 0);

    for (int t = 0; t < SEQ; ++t) {
        const uint* hb = ((t & 1) ? hpB : hpA) + (size_t)g * 16384;
        uint*       hd = ((t & 1) ? hpA : hpB) + (size_t)g * 16384;
        const ull*  hb8 = (const ull*)hb;
        const uint  tg  = (uint)t & 3u;   // expected generation tag

        // ---- x loads first (oldest in vmcnt queue) ----
        const float* xt = x + (size_t)t * BATCH * DIN;
        const floatx8 xv0 = *(const floatx8*)(xt + (size_t)(mbase + n16) * DIN + w * 32 + quad * 8);
        const floatx8 xv1 = *(const floatx8*)(xt + (size_t)(mbase + 16 + n16) * DIN + w * 32 + quad * 8);

        // ---- optimistic h loads (4B words, loaded as 8B pairs) ----
        ull hv[2][2][4];
        #pragma unroll
        for (int s = 0; s < 2; ++s)
            #pragma unroll
            for (int mt = 0; mt < 2; ++mt) {
                const ull* base = hb8 + (size_t)(((2 * w + s) * 2 + mt) * 64 + lane) * 4;
                #pragma unroll
                for (int j2 = 0; j2 < 4; ++j2)
                    hv[s][mt][j2] = __hip_atomic_load(base + j2, __ATOMIC_RELAXED,
                                                      __HIP_MEMORY_SCOPE_AGENT);
            }
        __builtin_amdgcn_sched_barrier(0);

        floatx4 acc[2][4];
        #pragma unroll
        for (int mt = 0; mt < 2; ++mt)
            #pragma unroll
            for (int a = 0; a < 4; ++a)
                acc[mt][a] = (floatx4){0.f, 0.f, 0.f, 0.f};

        // ---- x part (overlaps the in-flight h loads) ----
        #pragma unroll
        for (int mt = 0; mt < 2; ++mt) {
            const floatx8 xv = mt ? xv1 : xv0;
            short8 Ah, Al;
            #pragma unroll
            for (int j = 0; j < 8; ++j) {
                const float v = xv[j];
                const unsigned short hbw = f32_bf16_rtne(v);
                Ah[j] = (short)hbw;
                Al[j] = (short)f32_bf16_rtne(v - bf16_f32(hbw));
            }
            MFMA3(Ah, Al, Bh[0][0], Bl[0][0], acc[mt][0])
            MFMA3(Ah, Al, Bh[1][0], Bl[1][0], acc[mt][1])
            MFMA3(Ah, Al, Bh[2][0], Bl[2][0], acc[mt][2])
        }

        // ---- tag check; retry stale words with backoff ----
        {
            bool okk = true;
            #pragma unroll
            for (int s = 0; s < 2; ++s)
                #pragma unroll
                for (int mt = 0; mt < 2; ++mt)
                    #pragma unroll
                    for (int j2 = 0; j2 < 4; ++j2) {
                        const ull v = hv[s][mt][j2];
                        okk = okk && (((uint)(v >> 16) & 3u) == tg) &&
                                     (((uint)(v >> 48) & 3u) == tg);
                    }
            while (!__all(okk)) {
                __builtin_amdgcn_s_sleep(1);
                okk = true;
                #pragma unroll
                for (int s = 0; s < 2; ++s)
                    #pragma unroll
                    for (int mt = 0; mt < 2; ++mt) {
                        const ull* base = hb8 + (size_t)(((2 * w + s) * 2 + mt) * 64 + lane) * 4;
                        #pragma unroll
                        for (int j2 = 0; j2 < 4; ++j2) {
                            ull v = hv[s][mt][j2];
                            const bool stale = (((uint)(v >> 16) & 3u) != tg) ||
                                               (((uint)(v >> 48) & 3u) != tg);
                            if (stale) {
                                v = __hip_atomic_load(base + j2, __ATOMIC_RELAXED,
                                                      __HIP_MEMORY_SCOPE_AGENT);
                                hv[s][mt][j2] = v;
                            }
                            okk = okk && (((uint)(v >> 16) & 3u) == tg) &&
                                         (((uint)(v >> 48) & 3u) == tg);
                        }
                    }
            }
        }

        // ---- h part ----
        #pragma unroll
        for (int s = 0; s < 2; ++s)
            #pragma unroll
            for (int mt = 0; mt < 2; ++mt) {
                union { int i[8]; short8 s8[2]; } U;
                #pragma unroll
                for (int j2 = 0; j2 < 4; ++j2) {
                    const uint w0 = (uint)hv[s][mt][j2];
                    const uint w1 = (uint)(hv[s][mt][j2] >> 32);
                    U.i[j2]     = (int)((w0 & 0xFFFFu) | (w1 << 16));        // hi pair
                    U.i[4 + j2] = (int)((w0 >> 16) | (w1 & 0xFFFF0000u));    // lo pair
                }
                const short8 Ah = U.s8[0];
                const short8 Al = U.s8[1];
                MFMA3(Ah, Al, Bh[0][1 + s], Bl[0][1 + s], acc[mt][0])
                MFMA3(Ah, Al, Bh[1][1 + s], Bl[1][1 + s], acc[mt][1])
                MFMA3(Ah, Al, Bh[2][1 + s], Bl[2][1 + s], acc[mt][3])
            }
#undef MFMA3

        // ---- single-shot K-split reduction: 8 regions, one barrier ----
        #pragma unroll
        for (int mt = 0; mt < 2; ++mt)
            #pragma unroll
            for (int a = 0; a < 4; ++a)
                *(floatx4*)&P8[w][mt][a][n16][quad * 4] = acc[mt][a];
        lds_barrier();

        float sR = 0.f, sZ = 0.f, sNI = 0.f, sNH = 0.f;
        {
            const int mt = ob >> 4, rw = ob & 15;
            #pragma unroll
            for (int r = 0; r < 8; ++r) {
                sR  += P8[r][mt][0][ou][rw];
                sZ  += P8[r][mt][1][ou][rw];
                sNI += P8[r][mt][2][ou][rw];
                sNH += P8[r][mt][3][ou][rw];
            }
        }

        // ---- epilogue: gates, h update, tagged 4B store (gen = t+1) ----
        {
            const float r = sigmoidf_(sR);
            const float z = sigmoidf_(sZ);
            const float n = tanhf(sNI + r * sNH);
            const float hn = (1.0f - z) * n + z * hp;
            hp = hn;
            const unsigned short hbi = f32_bf16_rtne(hn);
            unsigned short lbi = f32_bf16_rtne(hn - bf16_f32(hbi));
            lbi = (unsigned short)((lbi & 0xFFFCu) | ((uint)(t + 1) & 3u));
            const uint word = (uint)hbi | ((uint)lbi << 16);
            __hip_atomic_store(hd + my_widx, word, __ATOMIC_RELAXED,
                               __HIP_MEMORY_SCOPE_AGENT);
        }

        lds_barrier();   // protect P8 reuse; h-store ack NOT waited here
    }
}

// --- attention / sigma / mu (reads packed final h; tag noise in lo is
//     ~h*2^-13, far below tolerance) ---
__global__ __launch_bounds__(256) void attn_kernel(
    const uint* __restrict__ hpk,        // packed frag-layout final h
    const float* __restrict__ external,
    const float* __restrict__ w_alpha,
    const float* __restrict__ w_sigma,
    float* __restrict__ mu,
    float* __restrict__ inv_sig,
    float* __restrict__ log_det)
{
    const int b = blockIdx.x;
    const int t = threadIdx.x;

    __shared__ float hs[HID];
    __shared__ float al[HIST];
    __shared__ float red[256];

    const int g = b >> 5, bl = b & 31;
    for (int k = t; k < HID; k += 256) {
        const uint wv = hpk[(size_t)g * 16384 + h_widx(bl, k)];
        hs[k] = bf16_f32((unsigned short)(wv & 0xFFFF)) +
                bf16_f32((unsigned short)(wv >> 16));
    }
    __syncthreads();

    const float4* hs4 = (const float4*)hs;

    float lg[8];
    #pragma unroll
    for (int i = 0; i < 8; ++i) {
        const int e = t + 256 * i;
        const float4* wr = (const float4*)(w_alpha + (size_t)e * HID);
        float acc = 0.f;
        #pragma unroll 4
        for (int k = 0; k < HID / 4; ++k) {
            const float4 w4 = wr[k];
            const float4 h4 = hs4[k];
            acc += w4.x * h4.x + w4.y * h4.y + w4.z * h4.z + w4.w * h4.w;
        }
        lg[i] = acc;
    }

    float m = lg[0];
    #pragma unroll
    for (int i = 1; i < 8; ++i) m = fmaxf(m, lg[i]);
    red[t] = m;
    __syncthreads();
    for (int off = 128; off > 0; off >>= 1) {
        if (t < off) red[t] = fmaxf(red[t], red[t + off]);
        __syncthreads();
    }
    m = red[0];
    __syncthreads();

    float s = 0.f;
    #pragma unroll
    for (int i = 0; i < 8; ++i) {
        const float v = __expf(lg[i] - m);
        al[t + 256 * i] = v;
        s += v;
    }
    red[t] = s;
    __syncthreads();
    for (int off = 128; off > 0; off >>= 1) {
        if (t < off) red[t] += red[t + off];
        __syncthreads();
    }
    s = red[0];
    const float inv_s = 1.0f / s;
    __syncthreads();

    const int d = t;
    float acc_mu = 0.f;
    #pragma unroll 8
    for (int e = 0; e < HIST; ++e) {
        acc_mu += al[e] * external[(size_t)e * DIN + d];
    }
    mu[(size_t)b * DIN + d] = acc_mu * inv_s;

    const float4* ws = (const float4*)(w_sigma + (size_t)d * HID);
    float sl = 0.f;
    #pragma unroll 4
    for (int k = 0; k < HID / 4; ++k) {
        const float4 w4 = ws[k];
        const float4 h4 = hs4[k];
        sl += w4.x * h4.x + w4.y * h4.y + w4.z * h4.z + w4.w * h4.w;
    }
    inv_sig[(size_t)b * DIN + d] = __expf(-sl);

    red[t] = sl;
    __syncthreads();
    for (int off = 128; off > 0; off >>= 1) {
        if (t < off) red[t] += red[t + off];
        __syncthreads();
    }
    if (t == 0) log_det[b] = red[0];
}

__global__ __launch_bounds__(256) void out_kernel(
    const float* __restrict__ x,
    const float* __restrict__ mu,
    const float* __restrict__ inv_sig,
    const float* __restrict__ log_det,
    float* __restrict__ out)
{
    const int s = blockIdx.x;
    const int b = threadIdx.x;
    const float4* xr = (const float4*)(x + ((size_t)s * BATCH + b) * DIN);
    const float4* mr = (const float4*)(mu + (size_t)b * DIN);
    const float4* ir = (const float4*)(inv_sig + (size_t)b * DIN);

    float maha = 0.f;
    #pragma unroll 8
    for (int k = 0; k < DIN / 4; ++k) {
        const float4 xv = xr[k];
        const float4 mv = mr[k];
        const float4 iv = ir[k];
        const float t0 = (xv.x - mv.x) * iv.x;
        const float t1 = (xv.y - mv.y) * iv.y;
        const float t2 = (xv.z - mv.z) * iv.z;
        const float t3 = (xv.w - mv.w) * iv.w;
        maha += t0 * t0 + t1 * t1 + t2 * t2 + t3 * t3;
    }
    const float LOG2PI = 1.8378770664093453f;
    out[(size_t)s * BATCH + b] = -0.5f * (maha + (float)DIN * LOG2PI) - log_det[b];
}

extern "C" void kernel_launch(void* const* d_in, const int* in_sizes, int n_in,
                              void* d_out, int out_size, void* d_ws, size_t ws_size,
                              hipStream_t stream)
{
    const float* x        = (const float*)d_in[0];
    const float* hidden   = (const float*)d_in[1];
    const float* external = (const float*)d_in[2];
    const float* w_ih     = (const float*)d_in[3];
    const float* w_hh     = (const float*)d_in[4];
    const float* w_alpha  = (const float*)d_in[5];
    const float* w_sigma  = (const float*)d_in[6];

    const int NH  = BATCH * HID;      // 131072
    const int NIH = 3 * HID * DIN;    // 393216
    const int NHH = 3 * HID * HID;    // 786432

    char* p = (char*)d_ws;
    uint* hpA = (uint*)p;             p += (size_t)NH * 4;
    uint* hpB = (uint*)p;             p += (size_t)NH * 4;
    short* wih_hi = (short*)p;        p += (size_t)NIH * 2;
    short* wih_lo = (short*)p;        p += (size_t)NIH * 2;
    short* whh_hi = (short*)p;        p += (size_t)NHH * 2;
    short* whh_lo = (short*)p;        p += (size_t)NHH * 2;
    float* mu      = (float*)p;       p += (size_t)BATCH * DIN * 4;
    float* inv_sig = (float*)p;       p += (size_t)BATCH * DIN * 4;
    float* log_det = (float*)p;       p += (size_t)BATCH * 4;

    // hpB must start with tag bits != 1 (consumers at t=1 expect gen 1);
    // zeros have tag 0 -> correctly treated as stale. hpA gets gen-0 data.
    (void)hipMemsetAsync(hpB, 0, (size_t)NH * 4, stream);

    split_kernel<<<(NIH + 255) / 256, 256, 0, stream>>>(w_ih, wih_hi, wih_lo, NIH);
    split_kernel<<<(NHH + 255) / 256, 256, 0, stream>>>(w_hh, whh_hi, whh_lo, NHH);
    pack_h_init<<<(NH + 255) / 256, 256, 0, stream>>>(hidden, hpA);

    gru_persistent<<<dim3(NBLK), dim3(512), 0, stream>>>(
        x, hidden, hpA, hpB, wih_hi, wih_lo, whh_hi, whh_lo);
    // t=511 (odd) writes hpA -> final packed h in hpA

    attn_kernel<<<dim3(BATCH), dim3(256), 0, stream>>>(
        hpA, external, w_alpha, w_sigma, mu, inv_sig, log_det);

    out_kernel<<<dim3(SEQ), dim3(256), 0, stream>>>(
        x, mu, inv_sig, log_det, (float*)d_out);
}